// Round 5
// baseline (1728.013 us; speedup 1.0000x reference)
//
#include <hip/hip_runtime.h>
#include <math.h>

#define B_ 512
#define T_ 200
#define D_ 256
#define H_ 256

typedef unsigned int   u32;
typedef unsigned short u16;
typedef _Float16 f16x8 __attribute__((ext_vector_type(8)));
typedef float    f32x4 __attribute__((ext_vector_type(4)));
typedef _Float16 h2 __attribute__((ext_vector_type(2)));

__device__ __forceinline__ float sigmoid_f(float x) { return 1.0f / (1.0f + __expf(-x)); }
__device__ __forceinline__ float tanh_f(float x)    { return 1.0f - 2.0f / (__expf(2.0f * x) + 1.0f); }

__device__ __forceinline__ u32 pack2h(float a, float b) {
    union { h2 h; u32 u; } r;
    r.h.x = (_Float16)a; r.h.y = (_Float16)b; return r.u;
}

// ============================================================================
// Projection GEMM (unchanged from R3/R4): proj = x @ W_x (+bias), all (b,t).
//   gy 0..3: gate cols -> f16 pairs packed into d_out (u32 view)
//   gy 4..5: cand cols -> f16 into ws
// ============================================================================
__global__ __launch_bounds__(256) void proj_x(
    const float* __restrict__ x,  const float* __restrict__ gk,
    const float* __restrict__ gb, const float* __restrict__ ck,
    const float* __restrict__ cb,
    u32* pg,                      // aliases d_out: [102400][256] u32 (512 f16)
    u16* __restrict__ pc)         // ws: [102400][256] f16
{
    __shared__ float xs[64][128];
    const int  tid  = threadIdx.x;
    const int  m0   = blockIdx.x * 64;
    const int  gy   = blockIdx.y;
    const bool isG  = (gy < 4);
    const int  nc   = isG ? 512 : 256;
    const int  c4   = (isG ? gy * 128 : (gy - 4) * 128) + 4 * (tid & 31);
    const int  rg   = tid >> 5;
    const float* W  = isG ? gk : ck;

    float acc[8][4] = {};

    for (int ks = 0; ks < 256; ks += 128) {
        __syncthreads();
        #pragma unroll
        for (int q = 0; q < 8; ++q) {
            int f = tid + 256 * q;
            int r = f >> 5, cq = f & 31;
            *(float4*)&xs[r][4 * cq] =
                *(const float4*)&x[(size_t)(m0 + r) * 256 + ks + 4 * cq];
        }
        __syncthreads();
        for (int kk = 0; kk < 128; kk += 4) {
            float4 w0 = *(const float4*)&W[(size_t)(ks + kk + 0) * nc + c4];
            float4 w1 = *(const float4*)&W[(size_t)(ks + kk + 1) * nc + c4];
            float4 w2 = *(const float4*)&W[(size_t)(ks + kk + 2) * nc + c4];
            float4 w3 = *(const float4*)&W[(size_t)(ks + kk + 3) * nc + c4];
            #pragma unroll
            for (int i = 0; i < 8; ++i) {
                float4 xv = *(const float4*)&xs[rg * 8 + i][kk];
                acc[i][0] = fmaf(xv.x, w0.x, acc[i][0]); acc[i][0] = fmaf(xv.y, w1.x, acc[i][0]);
                acc[i][0] = fmaf(xv.z, w2.x, acc[i][0]); acc[i][0] = fmaf(xv.w, w3.x, acc[i][0]);
                acc[i][1] = fmaf(xv.x, w0.y, acc[i][1]); acc[i][1] = fmaf(xv.y, w1.y, acc[i][1]);
                acc[i][1] = fmaf(xv.z, w2.y, acc[i][1]); acc[i][1] = fmaf(xv.w, w3.y, acc[i][1]);
                acc[i][2] = fmaf(xv.x, w0.z, acc[i][2]); acc[i][2] = fmaf(xv.y, w1.z, acc[i][2]);
                acc[i][2] = fmaf(xv.z, w2.z, acc[i][2]); acc[i][2] = fmaf(xv.w, w3.z, acc[i][2]);
                acc[i][3] = fmaf(xv.x, w0.w, acc[i][3]); acc[i][3] = fmaf(xv.y, w1.w, acc[i][3]);
                acc[i][3] = fmaf(xv.z, w2.w, acc[i][3]); acc[i][3] = fmaf(xv.w, w3.w, acc[i][3]);
            }
        }
    }

    const float* bias = isG ? gb : cb;
    float b0v = bias[c4], b1v = bias[c4 + 1], b2v = bias[c4 + 2], b3v = bias[c4 + 3];
    #pragma unroll
    for (int i = 0; i < 8; ++i) {
        int m = m0 + rg * 8 + i;
        uint2 v;
        v.x = pack2h(acc[i][0] + b0v, acc[i][1] + b1v);
        v.y = pack2h(acc[i][2] + b2v, acc[i][3] + b3v);
        if (isG) *(uint2*)&pg[(size_t)m * 256 + (c4 >> 1)] = v;
        else     *(uint2*)&pc[(size_t)m * 256 + c4]        = v;
    }
}

// ============================================================================
// Recurrent kernel v3: MFMA on the matrix pipe.
// 32 blocks x 512 threads (8 waves = 2/SIMD), 16 batch rows/block.
// Per step: gates [16x256]@[256x512] = 256 MFMA; cand [16x256]@[256x256] = 128.
// Weights register-resident as B-fragments: wave w owns gate N-tiles 4w..4w+3
// and cand N-tiles 2w..2w+1 -> 192 VGPRs/lane (f16).
// A-fragments (h / r*h) from LDS, row stride 264 f16 (2-way min conflicts).
// x-projections staged global->LDS each step. 3 barriers/step.
// C/D layout: col = lane&15, row = (lane>>4)*4 + reg  [m89-verified].
// A: A[m=lane&15][k=(lane>>4)*8+j]; B: B[k=(lane>>4)*8+j][n=lane&15].
// ============================================================================
__global__ __launch_bounds__(512, 2) void gru_rec3(
    const int*   __restrict__ slen,
    const float* __restrict__ gk, const float* __restrict__ ck,
    const u16* pg,                 // aliases d_out (gate x-proj f16, [b][t][512])
    const u16* __restrict__ pc,    // ws (cand x-proj f16, [b][t][256])
    float* out)                    // aliases pg (read(b,t) before write(b,t))
{
    __shared__ _Float16 hls[16][264];   // h
    __shared__ _Float16 rls[16][264];   // r*h
    __shared__ _Float16 uls[16][264];   // u gate
    __shared__ _Float16 gpl[16][520];   // gate x-proj, this step
    __shared__ _Float16 cpl[16][264];   // cand x-proj, this step

    const int tid  = threadIdx.x;
    const int lane = tid & 63;
    const int w    = tid >> 6;       // wave 0..7
    const int c    = lane & 15;      // MFMA col (n) / A row (m)
    const int q    = lane >> 4;      // quad
    const int b0   = blockIdx.x * 16;

    // ---- one-time: recurrent weights -> B-fragments in registers ----
    f16x8 wg[4][8];    // gate tiles 4w+g, K-step kq: B[k][n], k=32kq+8q+j
    f16x8 wcn[2][8];   // cand tiles 2w+g
    #pragma unroll
    for (int g = 0; g < 4; ++g) {
        const int col = (4 * w + g) * 16 + c;
        #pragma unroll
        for (int kq = 0; kq < 8; ++kq) {
            f16x8 v;
            #pragma unroll
            for (int j = 0; j < 8; ++j)
                v[j] = (_Float16)gk[(size_t)(256 + kq * 32 + q * 8 + j) * 512 + col];
            wg[g][kq] = v;
        }
    }
    #pragma unroll
    for (int g = 0; g < 2; ++g) {
        const int col = (2 * w + g) * 16 + c;
        #pragma unroll
        for (int kq = 0; kq < 8; ++kq) {
            f16x8 v;
            #pragma unroll
            for (int j = 0; j < 8; ++j)
                v[j] = (_Float16)ck[(size_t)(256 + kq * 32 + q * 8 + j) * 256 + col];
            wcn[g][kq] = v;
        }
    }

    int lenq[4];
    #pragma unroll
    for (int i = 0; i < 4; ++i) lenq[i] = slen[b0 + 4 * q + i];

    // init h = 0 (flat over the padded array; pads harmless)
    {
        _Float16* hz = &hls[0][0];
        for (int i = tid; i < 16 * 264; i += 512) hz[i] = (_Float16)0.0f;
    }

    for (int t = 0; t < T_; ++t) {
        // ---- issue this step's x-proj loads (2 gate rows + 2 cand rows / wave)
        const u16* pg0 = pg + ((size_t)(b0 + 2 * w + 0) * T_ + t) * 512;
        const u16* pg1 = pg + ((size_t)(b0 + 2 * w + 1) * T_ + t) * 512;
        const u16* pc0 = pc + ((size_t)(b0 + 2 * w + 0) * T_ + t) * 256;
        const u16* pc1 = pc + ((size_t)(b0 + 2 * w + 1) * T_ + t) * 256;
        const uint4 gv0 = *(const uint4*)(pg0 + lane * 8);
        const uint4 gv1 = *(const uint4*)(pg1 + lane * 8);
        const uint2 cv0 = *(const uint2*)(pc0 + lane * 4);
        const uint2 cv1 = *(const uint2*)(pc1 + lane * 4);

        __syncthreads();   // A: h(t-1) writes visible; prev proj consumers done

        // ---- gate K-loop: C[16x(64 cols of this wave)] ----
        f32x4 ag[4] = {};
        #pragma unroll
        for (int kq = 0; kq < 8; ++kq) {
            f16x8 af = *(const f16x8*)&hls[c][kq * 32 + q * 8];
            ag[0] = __builtin_amdgcn_mfma_f32_16x16x32_f16(af, wg[0][kq], ag[0], 0, 0, 0);
            ag[1] = __builtin_amdgcn_mfma_f32_16x16x32_f16(af, wg[1][kq], ag[1], 0, 0, 0);
            ag[2] = __builtin_amdgcn_mfma_f32_16x16x32_f16(af, wg[2][kq], ag[2], 0, 0, 0);
            ag[3] = __builtin_amdgcn_mfma_f32_16x16x32_f16(af, wg[3][kq], ag[3], 0, 0, 0);
        }

        // ---- land staged proj into LDS (overlaps MFMA latency) ----
        *(uint4*)&gpl[2 * w + 0][lane * 8] = gv0;
        *(uint4*)&gpl[2 * w + 1][lane * 8] = gv1;
        *(uint2*)&cpl[2 * w + 0][lane * 4] = cv0;
        *(uint2*)&cpl[2 * w + 1][lane * 4] = cv1;

        __syncthreads();   // G: gate accs done (all waves), proj in LDS

        // ---- gate epilogue: waves 0..3 = reset cols, 4..7 = update cols ----
        #pragma unroll
        for (int g = 0; g < 4; ++g) {
            const int cg = (4 * w + g) * 16 + c;
            #pragma unroll
            for (int i = 0; i < 4; ++i) {
                const int r = 4 * q + i;
                float gg = sigmoid_f(ag[g][i] + (float)gpl[r][cg]);
                if (w < 4) rls[r][cg]       = (_Float16)(gg * (float)hls[r][cg]);
                else       uls[r][cg - 256] = (_Float16)gg;
            }
        }
        __syncthreads();   // B: rls/uls ready

        // ---- candidate K-loop ----
        f32x4 ac[2] = {};
        #pragma unroll
        for (int kq = 0; kq < 8; ++kq) {
            f16x8 rf = *(const f16x8*)&rls[c][kq * 32 + q * 8];
            ac[0] = __builtin_amdgcn_mfma_f32_16x16x32_f16(rf, wcn[0][kq], ac[0], 0, 0, 0);
            ac[1] = __builtin_amdgcn_mfma_f32_16x16x32_f16(rf, wcn[1][kq], ac[1], 0, 0, 0);
        }

        // ---- cand epilogue + h update + output ----
        #pragma unroll
        for (int g = 0; g < 2; ++g) {
            const int cc = (2 * w + g) * 16 + c;
            #pragma unroll
            for (int i = 0; i < 4; ++i) {
                const int r = 4 * q + i;
                float cd   = tanh_f(ac[g][i] + (float)cpl[r][cc]);
                float u    = (float)uls[r][cc];
                float hold = (float)hls[r][cc];
                float hn   = u * hold + (1.0f - u) * cd;
                bool  valid = (t < lenq[i]);
                out[((size_t)(b0 + r) * T_ + t) * 256 + cc] = valid ? hn : 0.0f;
                if (valid) hls[r][cc] = (_Float16)hn;
            }
        }
    }
}

extern "C" void kernel_launch(void* const* d_in, const int* in_sizes, int n_in,
                              void* d_out, int out_size, void* d_ws, size_t ws_size,
                              hipStream_t stream) {
    const float* x    = (const float*)d_in[0];
    const int*   slen = (const int*)  d_in[1];
    const float* gk   = (const float*)d_in[2];
    const float* gb   = (const float*)d_in[3];
    const float* ck   = (const float*)d_in[4];
    const float* cb   = (const float*)d_in[5];
    float* out = (float*)d_out;
    u32*   pg  = (u32*)d_out;
    u16*   pc  = (u16*)d_ws;   // 52.4 MB cand x-proj

    dim3 pgrid(1600, 6);
    proj_x<<<pgrid, 256, 0, stream>>>(x, gk, gb, ck, cb, pg, pc);
    gru_rec3<<<32, 512, 0, stream>>>(slen, gk, ck, (const u16*)pg, pc, out);
}